// Round 14
// baseline (600.822 us; speedup 1.0000x reference)
//
#include <hip/hip_runtime.h>

// Problem constants (B=4, C=64, H=W=192)
#define HH 192
#define WID 192
#define HW (HH*WID)          // 36864
#define CB 64
#define BB 4
#define NPOS (BB*HW)         // 147456

typedef __attribute__((ext_vector_type(8))) _Float16 half8v;
typedef __attribute__((ext_vector_type(4))) _Float16 half4v;
typedef __attribute__((ext_vector_type(2))) _Float16 half2v;
typedef __attribute__((ext_vector_type(4))) float f32x4;
typedef __attribute__((ext_vector_type(16))) float f32x16;

static __device__ inline half8v splat8(_Float16 x) {
    half8v v = {x, x, x, x, x, x, x, x};
    return v;
}

// x tensors: CHANNEL-PLANE fp16 layout x[b][plane=c>>3][hw][8ch] (16B/pos/plane).
// Weights: FRAGMENT-MAJOR fp16 wt[k][cs][o][8ch], cs = 8-channel chunk.
// Round 14: LDS is the shared per-CU bottleneck (round-13 PMC: conflicts =
// 33% extra LDS cycles, occupancy doubling bought only 11%). This round
// REMOVES LDS/VALU ops: (1) phase-A waves remapped (group, ct-half) so each
// bf is read ONCE per group (stage-1 phase-A LDS reads halved; weight loads
// doubled but L2-resident, off the LDS pipe); (2) fast-path bilinear masks
// elided (zero-filled staging makes them redundant -- bit-identical);
// (3) weight prep fused into one segmented dispatch.

// ---------------------------------------------------------------------------
// Weight prep, ALL tensors in one dispatch. Each segment remaps
// w[o][c][ki][kj] fp32 (OIHW) -> wt[k][cs][o][j] fp16 (fragment-major).
// ---------------------------------------------------------------------------
#define WSEG(S, KK, CO, OP, SRC, DST)                                          \
    if (idx < (S)) {                                                           \
        int k  = idx / ((OP) * 64);                                            \
        int r  = idx % ((OP) * 64);                                            \
        int cs = r / ((OP) * 8);                                               \
        int r2 = r % ((OP) * 8);                                               \
        int o  = r2 / 8;                                                       \
        int j  = r2 % 8;                                                       \
        int c  = cs * 8 + j;                                                   \
        float v = (o < (CO)) ? SRC[((size_t)o * 64 + c) * (KK) + k] : 0.f;     \
        DST[idx] = (_Float16)v;                                                \
        return;                                                                \
    }                                                                          \
    idx -= (S);

__global__ __launch_bounds__(256) void k_wthall(
    const float* __restrict__ dw1, const float* __restrict__ dw2,
    const float* __restrict__ dw3, const float* __restrict__ ow1,
    const float* __restrict__ ow2, const float* __restrict__ ow3,
    const float* __restrict__ w_in, const float* __restrict__ w_out,
    _Float16* __restrict__ wtd1, _Float16* __restrict__ wtd2,
    _Float16* __restrict__ wtd3, _Float16* __restrict__ wto1,
    _Float16* __restrict__ wto2, _Float16* __restrict__ wto3,
    _Float16* __restrict__ wtin, _Float16* __restrict__ wtou)
{
    int idx = blockIdx.x * 256 + threadIdx.x;
    WSEG(200704, 49, 64,  64, dw1,  wtd1)   // 7x7 deform
    WSEG(102400, 25, 64,  64, dw2,  wtd2)   // 5x5 deform
    WSEG( 36864,  9, 64,  64, dw3,  wtd3)   // 3x3 deform
    WSEG(204800, 25, 98, 128, ow1,  wto1)   // 5x5 offset (OP=128)
    WSEG(102400, 25, 50,  64, ow2,  wto2)   // 5x5 offset
    WSEG( 18432,  9, 18,  32, ow3,  wto3)   // 3x3 offset
    WSEG(  8192,  1, 128, 128, w_in, wtin)  // 1x1 in (C->2C)
    WSEG(  4096,  1, 64,  64, w_out, wtou)  // 1x1 out
}
#undef WSEG

// ---------------------------------------------------------------------------
// K1 (MFMA): LayerNorm over C + 1x1 conv C->2C via 32x32x16 MFMA.
// ---------------------------------------------------------------------------
__global__ __launch_bounds__(256) void k_lnconv_mfma(
    const float* __restrict__ x, const float* __restrict__ g, const float* __restrict__ be,
    const _Float16* __restrict__ wt_in, const float* __restrict__ b_in,
    _Float16* __restrict__ x1, _Float16* __restrict__ x2)
{
    int p0  = blockIdx.x * 128;
    int b   = p0 / HW;
    int hwb = p0 % HW;

    int lane = threadIdx.x & 63;
    int wave = threadIdx.x >> 6;
    int l31  = lane & 31;
    int h    = lane >> 5;
    int pos  = hwb + wave * 32 + l31;

    const float* xp = x + (size_t)b * CB * HW + pos;

    float v[32];
    float sum = 0.f, sumsq = 0.f;
#pragma unroll
    for (int m = 0; m < 4; m++)
#pragma unroll
        for (int j = 0; j < 8; j++) {
            float t = xp[(size_t)(m * 16 + h * 8 + j) * HW];
            v[m * 8 + j] = t; sum += t; sumsq += t * t;
        }
    sum   += __shfl_xor(sum, 32);
    sumsq += __shfl_xor(sumsq, 32);
    float mu  = sum * (1.f / 64.f);
    float var = sumsq * (1.f / 64.f) - mu * mu;
    float inv = rsqrtf(var + 1e-5f);

    half8v bf[4];
#pragma unroll
    for (int m = 0; m < 4; m++)
#pragma unroll
        for (int j = 0; j < 8; j++) {
            int c = m * 16 + h * 8 + j;
            bf[m][j] = (_Float16)((v[m * 8 + j] - mu) * inv * g[c] + be[c]);
        }

    f32x16 acc[4];
#pragma unroll
    for (int tI = 0; tI < 4; tI++)
#pragma unroll
        for (int r = 0; r < 16; r++) acc[tI][r] = 0.f;

    const half8v* wbase = (const half8v*)wt_in;
#pragma unroll
    for (int m = 0; m < 4; m++) {
        int cs = m * 2 + h;
        const half8v* wp = wbase + (size_t)cs * 128;      // OP = 128
#pragma unroll
        for (int tI = 0; tI < 4; tI++) {
            half8v a = wp[tI * 32 + l31];
            acc[tI] = __builtin_amdgcn_mfma_f32_32x32x16_f16(a, bf[m], acc[tI], 0, 0, 0);
        }
    }

    _Float16* o1 = x1 + (size_t)b * HW * 64 + (size_t)pos * 8;
    _Float16* o2 = x2 + (size_t)b * HW * 64 + (size_t)pos * 8;
#pragma unroll
    for (int tI = 0; tI < 4; tI++) {
        _Float16* ob = (tI < 2) ? o1 : o2;
        int obase = (tI & 1) * 32;
#pragma unroll
        for (int gidx = 0; gidx < 4; gidx++) {
            int o = obase + gidx * 8 + 4 * h;
            float4 bb = *(const float4*)&b_in[tI * 32 + gidx * 8 + 4 * h];
            half4v r;
            r[0] = (_Float16)(acc[tI][gidx * 4 + 0] + bb.x);
            r[1] = (_Float16)(acc[tI][gidx * 4 + 1] + bb.y);
            r[2] = (_Float16)(acc[tI][gidx * 4 + 2] + bb.z);
            r[3] = (_Float16)(acc[tI][gidx * 4 + 3] + bb.w);
            *(half4v*)&ob[(size_t)(o >> 3) * HW * 8 + (o & 7)] = r;
        }
    }
}

// ---------------------------------------------------------------------------
// k_fconv v3: FUSED offset+deform conv, 512 threads / 8 waves per 16x8 tile.
// Phase A: wave = (group gA = wave&3, ct-half ctH = wave>>2); each wave reads
// bf ONCE per (tap,m) and runs CPW weight-loads+MFMAs (stage-1 LDS reads /2).
// Phase B: tap-split wave-groups + LDS partial-sum reduction (round 13).
// Fast-path masks elided (zero-fill staging makes them redundant).
// ---------------------------------------------------------------------------
template<int KD, int PAD, int HALO, int KO, int PADO, int CT>
__global__ __launch_bounds__(512) void k_fconv(
    const _Float16* __restrict__ xin,
    const _Float16* __restrict__ wto, const float* __restrict__ obias,
    const _Float16* __restrict__ wtd, const float* __restrict__ dbias,
    _Float16* __restrict__ outp)
{
    constexpr int KKD = KD * KD;          // deform taps = offset channel pairs
    constexpr int KKO = KO * KO;          // offset-conv taps
    constexpr int RB = 16 + 2 * HALO;
    constexpr int WB = 8  + 2 * HALO;
    constexpr int OP = CT * 32;
    constexpr int CPW = (CT + 1) / 2;     // ct tiles per wave (2 for CT=4 else 1)
    constexpr int THALF = (KKD + 1) / 2;  // phase-B tap split point

    __shared__ half8v sm[RB * WB * 8];    // staged tile; later: partial-acc buf
    __shared__ unsigned int offs[KKD * 128];  // fp16 half2 offset per (tap,pos)

    int bi  = blockIdx.x;
    int b   = bi / 288;                   // 288 = 12 row-tiles * 24 col-tiles
    int tt  = bi % 288;
    int by0 = (tt / 24) * 16;
    int bx0 = (tt % 24) * 8;
    int ry0 = by0 - HALO;
    int rx0 = bx0 - HALO;

    const _Float16* xb = xin + (size_t)b * HW * 64;

    // ---- stage tile + halo via global_load_lds, ZERO-FILL outside image ----
    {
        _Float16* smlin = (_Float16*)sm;
        constexpr int CH = RB * WB * 8;
        for (int i0 = 0; i0 < CH; i0 += 512) {
            int i    = i0 + (int)threadIdx.x;
            int wbse = i0 + ((int)threadIdx.x & 448);    // wave-uniform chunk base
            if (i < CH) {
                int pix = i >> 3;
                int ts  = i & 7;
                int pl  = ts ^ (pix & 7);
                int r   = pix / WB;
                int cc  = pix - r * WB;
                int yr  = ry0 + r;
                int xc  = rx0 + cc;
                bool ok = (yr >= 0 && yr < HH && xc >= 0 && xc < WID);
                if (ok) {
                    const _Float16* src = xb + ((size_t)pl * HW + (size_t)(yr * WID + xc)) * 8;
                    __builtin_amdgcn_global_load_lds(src, &smlin[(size_t)wbse * 8], 16, 0, 0);
                } else {
                    *(half8v*)&smlin[(size_t)i * 8] = splat8((_Float16)0.f);
                }
            }
        }
    }
    __syncthreads();

    int lane = threadIdx.x & 63;
    int wave = threadIdx.x >> 6;          // 0..7
    int l31  = lane & 31;
    int h    = lane >> 5;
    int prow = l31 >> 3;                  // 0..3
    int pcol = l31 & 7;                   // 0..7
    int xt   = bx0 + pcol;

    // =========================== phase A: offset conv ======================
    {
        int gA  = wave & 3;               // position group this wave serves
        int ctH = wave >> 2;              // ct-half this wave owns

        int ytA = by0 + gA * 4 + prow;
        int pAb = gA * 32 + l31;          // block-local position index

        const half8v* wbase = (const half8v*)wto;

        f32x16 accO[CPW];
#pragma unroll
        for (int u = 0; u < CPW; u++)
#pragma unroll
            for (int r = 0; r < 16; r++) accO[u][r] = 0.f;

        int ki = 0, kj = 0;
        for (int k = 0; k < KKO; k++) {
            int pixA = ((ytA + ki - PADO) - ry0) * WB + ((xt + kj - PADO) - rx0);

#pragma unroll
            for (int m = 0; m < 4; m++) {
                int cs = m * 2 + h;
                half8v bf = sm[pixA * 8 + (cs ^ (pixA & 7))];
                const half8v* wp = wbase + ((size_t)k * 8 + cs) * OP;
#pragma unroll
                for (int u = 0; u < CPW; u++) {
                    int ct = ctH * CPW + u;
                    if (ct < CT) {
                        half8v a = wp[ct * 32 + l31];
                        accO[u] = __builtin_amdgcn_mfma_f32_32x32x16_f16(a, bf, accO[u], 0, 0, 0);
                    }
                }
            }

            kj++;
            if (kj == KO) { kj = 0; ki++; }
        }

        // epilogue A -> LDS offsets: o = ct*32 + 8gi + 4h + 2pr; tap = o/2
#pragma unroll
        for (int u = 0; u < CPW; u++) {
            int ct = ctH * CPW + u;
            if (ct < CT) {
#pragma unroll
                for (int gi = 0; gi < 4; gi++) {
                    int obase = ct * 32 + 8 * gi + 4 * h;
#pragma unroll
                    for (int pr = 0; pr < 2; pr++) {
                        int o  = obase + 2 * pr;
                        int kt = o >> 1;
                        if (kt < KKD) {
                            half2v hv;
                            hv[0] = (_Float16)(accO[u][gi * 4 + 2 * pr]     + obias[o]);
                            hv[1] = (_Float16)(accO[u][gi * 4 + 2 * pr + 1] + obias[o + 1]);
                            *(half2v*)&offs[kt * 128 + pAb] = hv;
                        }
                    }
                }
            }
        }
    }
    __syncthreads();

    // =========================== phase B: deform conv ======================
    int w4   = wave & 3;
    int grp  = wave >> 2;                 // tap group: 0 -> [0,THALF), 1 -> [THALF,KKD)
    int yt   = by0 + w4 * 4 + prow;
    int p128 = w4 * 32 + l31;

    const half8v* wbase = (const half8v*)wtd;

    f32x16 acc0 = {0.f,0.f,0.f,0.f,0.f,0.f,0.f,0.f,0.f,0.f,0.f,0.f,0.f,0.f,0.f,0.f};
    f32x16 acc1 = {0.f,0.f,0.f,0.f,0.f,0.f,0.f,0.f,0.f,0.f,0.f,0.f,0.f,0.f,0.f,0.f};

    int T0 = grp ? THALF : 0;
    int T1 = grp ? KKD : THALF;
    int ki = T0 / KD, kj = T0 % KD;
    for (int k = T0; k < T1; k++) {
        // offset for this tap & position: LDS broadcast read (lane pairs share)
        half2v ov = *(const half2v*)&offs[k * 128 + p128];
        float ox = (float)ov[0];
        float oy = (float)ov[1];

        // A-frags, fragment-major: wt[k][cs][o] -> lane-contiguous 16B
        half8v a0[4], a1[4];
#pragma unroll
        for (int m = 0; m < 4; m++) {
            int cs = m * 2 + h;
            const half8v* wp = wbase + ((size_t)k * 8 + cs) * 64;   // OP = 64
            a0[m] = wp[l31];
            a1[m] = wp[32 + l31];
        }

        float py = (float)(yt + ki - PAD) + ox;
        float px = (float)(xt + kj - PAD) + oy;
        float fy = floorf(py), fx = floorf(px);
        float wy = py - fy, wx = px - fx;
        int iy0 = (int)fy, ix0 = (int)fx;
        int iy1 = iy0 + 1, ix1 = ix0 + 1;

        bool fast = (iy0 >= ry0) && (iy1 <= ry0 + RB - 1) &&
                    (ix0 >= rx0) && (ix1 <= rx0 + WB - 1);

        if (__builtin_expect(fast, 1)) {
            // zero-filled staging => image-boundary masks redundant here
            half8v w00v = splat8((_Float16)((1.f - wy) * (1.f - wx)));
            half8v w01v = splat8((_Float16)((1.f - wy) * wx));
            half8v w10v = splat8((_Float16)(wy * (1.f - wx)));
            half8v w11v = splat8((_Float16)(wy * wx));
            int p00 = (iy0 - ry0) * WB + (ix0 - rx0);
            int p01 = p00 + 1, p10 = p00 + WB, p11 = p00 + WB + 1;
            int s00 = p00 & 7, s01 = p01 & 7, s10 = p10 & 7, s11 = p11 & 7;
#pragma unroll
            for (int m = 0; m < 4; m++) {
                int cs = m * 2 + h;
                half8v c00 = sm[p00 * 8 + (cs ^ s00)];
                half8v c01 = sm[p01 * 8 + (cs ^ s01)];
                half8v c10 = sm[p10 * 8 + (cs ^ s10)];
                half8v c11 = sm[p11 * 8 + (cs ^ s11)];
                half8v bf = c00 * w00v + c01 * w01v + c10 * w10v + c11 * w11v;
                acc0 = __builtin_amdgcn_mfma_f32_32x32x16_f16(a0[m], bf, acc0, 0, 0, 0);
                acc1 = __builtin_amdgcn_mfma_f32_32x32x16_f16(a1[m], bf, acc1, 0, 0, 0);
            }
        } else {
            float m00 = (iy0 >= 0 && iy0 < HH && ix0 >= 0 && ix0 < WID) ? 1.f : 0.f;
            float m01 = (iy0 >= 0 && iy0 < HH && ix1 >= 0 && ix1 < WID) ? 1.f : 0.f;
            float m10 = (iy1 >= 0 && iy1 < HH && ix0 >= 0 && ix0 < WID) ? 1.f : 0.f;
            float m11 = (iy1 >= 0 && iy1 < HH && ix1 >= 0 && ix1 < WID) ? 1.f : 0.f;
            half8v w00v = splat8((_Float16)((1.f - wy) * (1.f - wx) * m00));
            half8v w01v = splat8((_Float16)((1.f - wy) * wx * m01));
            half8v w10v = splat8((_Float16)(wy * (1.f - wx) * m10));
            half8v w11v = splat8((_Float16)(wy * wx * m11));
            int cy0 = min(max(iy0, 0), HH - 1), cy1 = min(max(iy1, 0), HH - 1);
            int cx0 = min(max(ix0, 0), WID - 1), cx1 = min(max(ix1, 0), WID - 1);
            size_t i00 = (size_t)(cy0 * WID + cx0) * 8, i01 = (size_t)(cy0 * WID + cx1) * 8;
            size_t i10 = (size_t)(cy1 * WID + cx0) * 8, i11 = (size_t)(cy1 * WID + cx1) * 8;
#pragma unroll
            for (int m = 0; m < 4; m++) {
                const _Float16* xq = xb + (size_t)(m * 2 + h) * HW * 8;
                half8v c00 = *(const half8v*)(xq + i00);
                half8v c01 = *(const half8v*)(xq + i01);
                half8v c10 = *(const half8v*)(xq + i10);
                half8v c11 = *(const half8v*)(xq + i11);
                half8v bf = c00 * w00v + c01 * w01v + c10 * w10v + c11 * w11v;
                acc0 = __builtin_amdgcn_mfma_f32_32x32x16_f16(a0[m], bf, acc0, 0, 0, 0);
                acc1 = __builtin_amdgcn_mfma_f32_32x32x16_f16(a1[m], bf, acc1, 0, 0, 0);
            }
        }

        kj++;
        if (kj == KD) { kj = 0; ki++; }
    }

    // ---- cross-group reduction: group 1 -> LDS (sm dead), group 0 adds ----
    __syncthreads();                      // all phase-B sm reads complete
    float* red = (float*)sm;              // 256 lanes * 32 floats = 32 KB
    if (grp == 1) {
        float* dst = red + ((size_t)(w4 * 64 + lane)) * 32;
#pragma unroll
        for (int r = 0; r < 16; r++) { dst[r] = acc0[r]; dst[16 + r] = acc1[r]; }
    }
    __syncthreads();
    if (grp == 0) {
        const float* src = red + ((size_t)(w4 * 64 + lane)) * 32;
#pragma unroll
        for (int r = 0; r < 16; r++) { acc0[r] += src[r]; acc1[r] += src[16 + r]; }

        // ---- epilogue B: D: pos = l31, o = t*32 + (r&3) + 8*(r>>2) + 4h ----
        int hwp = yt * WID + xt;
        _Float16* ob = outp + (size_t)b * HW * 64 + (size_t)hwp * 8 + 4 * h;
#pragma unroll
        for (int g = 0; g < 4; g++) {
            float4 bb0 = *(const float4*)&dbias[g * 8 + 4 * h];
            half4v r0;
            r0[0] = (_Float16)(acc0[g * 4 + 0] + bb0.x);
            r0[1] = (_Float16)(acc0[g * 4 + 1] + bb0.y);
            r0[2] = (_Float16)(acc0[g * 4 + 2] + bb0.z);
            r0[3] = (_Float16)(acc0[g * 4 + 3] + bb0.w);
            *(half4v*)&ob[(size_t)g * HW * 8] = r0;
            float4 bb1 = *(const float4*)&dbias[32 + g * 8 + 4 * h];
            half4v r1;
            r1[0] = (_Float16)(acc1[g * 4 + 0] + bb1.x);
            r1[1] = (_Float16)(acc1[g * 4 + 1] + bb1.y);
            r1[2] = (_Float16)(acc1[g * 4 + 2] + bb1.z);
            r1[3] = (_Float16)(acc1[g * 4 + 3] + bb1.w);
            *(half4v*)&ob[(size_t)(4 + g) * HW * 8] = r1;
        }
    }
}

// ---------------------------------------------------------------------------
// K4 (MFMA): h = x1_final + x2; out = h @ w_out^T + b_out + x (NCHW fp32).
// ---------------------------------------------------------------------------
__global__ __launch_bounds__(256) void k_merge_mfma(
    const _Float16* __restrict__ x1f, const _Float16* __restrict__ x2,
    const float* __restrict__ xin, const _Float16* __restrict__ wt_out,
    const float* __restrict__ b_out, float* __restrict__ out)
{
    int p0  = blockIdx.x * 128;
    int b   = p0 / HW;
    int hwb = p0 % HW;

    int lane = threadIdx.x & 63;
    int wave = threadIdx.x >> 6;
    int l31  = lane & 31;
    int h    = lane >> 5;
    int pos  = hwb + wave * 32 + l31;

    const _Float16* a1 = x1f + (size_t)b * HW * 64 + (size_t)pos * 8;
    const _Float16* a2 = x2  + (size_t)b * HW * 64 + (size_t)pos * 8;

    half8v bf[4];
#pragma unroll
    for (int m = 0; m < 4; m++) {
        int cs = m * 2 + h;
        half8v u1 = *(const half8v*)&a1[(size_t)cs * HW * 8];
        half8v u2 = *(const half8v*)&a2[(size_t)cs * HW * 8];
        bf[m] = u1 + u2;
    }

    f32x16 acc[2];
#pragma unroll
    for (int tI = 0; tI < 2; tI++)
#pragma unroll
        for (int r = 0; r < 16; r++) acc[tI][r] = 0.f;

    const half8v* wbase = (const half8v*)wt_out;
#pragma unroll
    for (int m = 0; m < 4; m++) {
        int cs = m * 2 + h;
        const half8v* wp = wbase + (size_t)cs * 64;       // OP = 64
#pragma unroll
        for (int tI = 0; tI < 2; tI++) {
            half8v a = wp[tI * 32 + l31];
            acc[tI] = __builtin_amdgcn_mfma_f32_32x32x16_f16(a, bf[m], acc[tI], 0, 0, 0);
        }
    }

    size_t base = (size_t)b * CB * HW + pos;
#pragma unroll
    for (int tI = 0; tI < 2; tI++) {
#pragma unroll
        for (int gidx = 0; gidx < 4; gidx++) {
            int o0 = tI * 32 + gidx * 8 + 4 * h;
#pragma unroll
            for (int i = 0; i < 4; i++) {
                int o = o0 + i;
                out[base + (size_t)o * HW] =
                    acc[tI][gidx * 4 + i] + b_out[o] + xin[base + (size_t)o * HW];
            }
        }
    }
}

// ---------------------------------------------------------------------------
// Launch. Workspace layout unchanged (off region unused). Weights ~1.5 MB
// fragment-major; wto1 OP=128; wt_in 16KB, wt_out 8KB.
// ---------------------------------------------------------------------------
extern "C" void kernel_launch(void* const* d_in, const int* in_sizes, int n_in,
                              void* d_out, int out_size, void* d_ws, size_t ws_size,
                              hipStream_t stream)
{
    const float* x     = (const float*)d_in[0];
    const float* ln_w  = (const float*)d_in[1];
    const float* ln_b  = (const float*)d_in[2];
    const float* w_in  = (const float*)d_in[3];
    const float* b_in  = (const float*)d_in[4];
    const float* w_out = (const float*)d_in[5];
    const float* b_out = (const float*)d_in[6];
    const float* dw1   = (const float*)d_in[7];
    const float* db1   = (const float*)d_in[8];
    const float* dw2   = (const float*)d_in[9];
    const float* db2   = (const float*)d_in[10];
    const float* dw3   = (const float*)d_in[11];
    const float* db3   = (const float*)d_in[12];
    const float* ow1   = (const float*)d_in[13];
    const float* ob1   = (const float*)d_in[14];
    const float* ow2   = (const float*)d_in[15];
    const float* ob2   = (const float*)d_in[16];
    const float* ow3   = (const float*)d_in[17];
    const float* ob3   = (const float*)d_in[18];

    _Float16* x1a = (_Float16*)d_ws;
    _Float16* x1b = x1a + (size_t)NPOS * 64;
    _Float16* x2  = x1b + (size_t)NPOS * 64;
    float* off = (float*)(x2 + (size_t)NPOS * 64);       // unused (kept for layout)
    _Float16* wtd1 = (_Float16*)(off + (size_t)NPOS * 100);
    _Float16* wtd2 = wtd1 + 49 * 64 * 64;
    _Float16* wtd3 = wtd2 + 25 * 64 * 64;
    _Float16* wto1 = wtd3 +  9 * 64 * 64;
    _Float16* wto2 = wto1 + 25 * 128 * 64;   // OP=128
    _Float16* wto3 = wto2 + 25 * 64 * 64;
    _Float16* wtin = wto3 +  9 * 32 * 64;
    _Float16* wtou = wtin + 128 * 64;

    // weight prep: ONE segmented dispatch (was 8 tiny launches)
    // total elems = 200704+102400+36864+204800+102400+18432+8192+4096 = 677888
    k_wthall<<<(677888 + 255) / 256, 256, 0, stream>>>(
        dw1, dw2, dw3, ow1, ow2, ow3, w_in, w_out,
        wtd1, wtd2, wtd3, wto1, wto2, wto3, wtin, wtou);

    // LN + 1x1 conv (MFMA)
    k_lnconv_mfma<<<NPOS / 128, 256, 0, stream>>>(x, ln_w, ln_b, wtin, b_in, x1a, x2);

    // fused offset+deform per stage (KD,PAD,HALO, KO,PADO, CT), 512 threads
    k_fconv<7, 3, 4, 5, 2, 4><<<1152, 512, 0, stream>>>(x1a, wto1, ob1, wtd1, db1, x1b);
    k_fconv<5, 2, 3, 5, 2, 2><<<1152, 512, 0, stream>>>(x1b, wto2, ob2, wtd2, db2, x1a);
    k_fconv<3, 1, 2, 3, 1, 1><<<1152, 512, 0, stream>>>(x1a, wto3, ob3, wtd3, db3, x1b);

    // merge + 1x1 conv + residual (MFMA)
    k_merge_mfma<<<NPOS / 128, 256, 0, stream>>>(x1b, x2, x, wtou, b_out, (float*)d_out);
}

// Round 15
// 475.261 us; speedup vs baseline: 1.2642x; 1.2642x over previous
//
#include <hip/hip_runtime.h>

// Problem constants (B=4, C=64, H=W=192)
#define HH 192
#define WID 192
#define HW (HH*WID)          // 36864
#define CB 64
#define BB 4
#define NPOS (BB*HW)         // 147456

typedef __attribute__((ext_vector_type(8))) _Float16 half8v;
typedef __attribute__((ext_vector_type(4))) _Float16 half4v;
typedef __attribute__((ext_vector_type(2))) _Float16 half2v;
typedef __attribute__((ext_vector_type(4))) float f32x4;
typedef __attribute__((ext_vector_type(16))) float f32x16;

static __device__ inline half8v splat8(_Float16 x) {
    half8v v = {x, x, x, x, x, x, x, x};
    return v;
}

// x tensors: CHANNEL-PLANE fp16 layout x[b][plane=c>>3][hw][8ch] (16B/pos/plane).
// Weights: FRAGMENT-MAJOR fp16 wt[k][cs][o][8ch], cs = 8-channel chunk.
// Round 15: REVERT of round-14's phase-A remap (refuted: swapping 800 LDS
// reads for 800 global weight loads per block cost 56% -- global-load count
// per MFMA is the scarce resource here, LDS reads are cheap). Phase A is
// round-13's proven (ct, pslot) layout verbatim. Kept from round 14: phase-B
// fast-path mask elision (bit-identical VALU removal) and the consolidated
// one-dispatch weight prep.

// ---------------------------------------------------------------------------
// Weight prep, ALL tensors in one dispatch. Each segment remaps
// w[o][c][ki][kj] fp32 (OIHW) -> wt[k][cs][o][j] fp16 (fragment-major).
// ---------------------------------------------------------------------------
#define WSEG(S, KK, CO, OP, SRC, DST)                                          \
    if (idx < (S)) {                                                           \
        int k  = idx / ((OP) * 64);                                            \
        int r  = idx % ((OP) * 64);                                            \
        int cs = r / ((OP) * 8);                                               \
        int r2 = r % ((OP) * 8);                                               \
        int o  = r2 / 8;                                                       \
        int j  = r2 % 8;                                                       \
        int c  = cs * 8 + j;                                                   \
        float v = (o < (CO)) ? SRC[((size_t)o * 64 + c) * (KK) + k] : 0.f;     \
        DST[idx] = (_Float16)v;                                                \
        return;                                                                \
    }                                                                          \
    idx -= (S);

__global__ __launch_bounds__(256) void k_wthall(
    const float* __restrict__ dw1, const float* __restrict__ dw2,
    const float* __restrict__ dw3, const float* __restrict__ ow1,
    const float* __restrict__ ow2, const float* __restrict__ ow3,
    const float* __restrict__ w_in, const float* __restrict__ w_out,
    _Float16* __restrict__ wtd1, _Float16* __restrict__ wtd2,
    _Float16* __restrict__ wtd3, _Float16* __restrict__ wto1,
    _Float16* __restrict__ wto2, _Float16* __restrict__ wto3,
    _Float16* __restrict__ wtin, _Float16* __restrict__ wtou)
{
    int idx = blockIdx.x * 256 + threadIdx.x;
    WSEG(200704, 49, 64,  64, dw1,  wtd1)   // 7x7 deform
    WSEG(102400, 25, 64,  64, dw2,  wtd2)   // 5x5 deform
    WSEG( 36864,  9, 64,  64, dw3,  wtd3)   // 3x3 deform
    WSEG(204800, 25, 98, 128, ow1,  wto1)   // 5x5 offset (OP=128)
    WSEG(102400, 25, 50,  64, ow2,  wto2)   // 5x5 offset
    WSEG( 18432,  9, 18,  32, ow3,  wto3)   // 3x3 offset
    WSEG(  8192,  1, 128, 128, w_in, wtin)  // 1x1 in (C->2C)
    WSEG(  4096,  1, 64,  64, w_out, wtou)  // 1x1 out
}
#undef WSEG

// ---------------------------------------------------------------------------
// K1 (MFMA): LayerNorm over C + 1x1 conv C->2C via 32x32x16 MFMA.
// ---------------------------------------------------------------------------
__global__ __launch_bounds__(256) void k_lnconv_mfma(
    const float* __restrict__ x, const float* __restrict__ g, const float* __restrict__ be,
    const _Float16* __restrict__ wt_in, const float* __restrict__ b_in,
    _Float16* __restrict__ x1, _Float16* __restrict__ x2)
{
    int p0  = blockIdx.x * 128;
    int b   = p0 / HW;
    int hwb = p0 % HW;

    int lane = threadIdx.x & 63;
    int wave = threadIdx.x >> 6;
    int l31  = lane & 31;
    int h    = lane >> 5;
    int pos  = hwb + wave * 32 + l31;

    const float* xp = x + (size_t)b * CB * HW + pos;

    float v[32];
    float sum = 0.f, sumsq = 0.f;
#pragma unroll
    for (int m = 0; m < 4; m++)
#pragma unroll
        for (int j = 0; j < 8; j++) {
            float t = xp[(size_t)(m * 16 + h * 8 + j) * HW];
            v[m * 8 + j] = t; sum += t; sumsq += t * t;
        }
    sum   += __shfl_xor(sum, 32);
    sumsq += __shfl_xor(sumsq, 32);
    float mu  = sum * (1.f / 64.f);
    float var = sumsq * (1.f / 64.f) - mu * mu;
    float inv = rsqrtf(var + 1e-5f);

    half8v bf[4];
#pragma unroll
    for (int m = 0; m < 4; m++)
#pragma unroll
        for (int j = 0; j < 8; j++) {
            int c = m * 16 + h * 8 + j;
            bf[m][j] = (_Float16)((v[m * 8 + j] - mu) * inv * g[c] + be[c]);
        }

    f32x16 acc[4];
#pragma unroll
    for (int tI = 0; tI < 4; tI++)
#pragma unroll
        for (int r = 0; r < 16; r++) acc[tI][r] = 0.f;

    const half8v* wbase = (const half8v*)wt_in;
#pragma unroll
    for (int m = 0; m < 4; m++) {
        int cs = m * 2 + h;
        const half8v* wp = wbase + (size_t)cs * 128;      // OP = 128
#pragma unroll
        for (int tI = 0; tI < 4; tI++) {
            half8v a = wp[tI * 32 + l31];
            acc[tI] = __builtin_amdgcn_mfma_f32_32x32x16_f16(a, bf[m], acc[tI], 0, 0, 0);
        }
    }

    _Float16* o1 = x1 + (size_t)b * HW * 64 + (size_t)pos * 8;
    _Float16* o2 = x2 + (size_t)b * HW * 64 + (size_t)pos * 8;
#pragma unroll
    for (int tI = 0; tI < 4; tI++) {
        _Float16* ob = (tI < 2) ? o1 : o2;
        int obase = (tI & 1) * 32;
#pragma unroll
        for (int gidx = 0; gidx < 4; gidx++) {
            int o = obase + gidx * 8 + 4 * h;
            float4 bb = *(const float4*)&b_in[tI * 32 + gidx * 8 + 4 * h];
            half4v r;
            r[0] = (_Float16)(acc[tI][gidx * 4 + 0] + bb.x);
            r[1] = (_Float16)(acc[tI][gidx * 4 + 1] + bb.y);
            r[2] = (_Float16)(acc[tI][gidx * 4 + 2] + bb.z);
            r[3] = (_Float16)(acc[tI][gidx * 4 + 3] + bb.w);
            *(half4v*)&ob[(size_t)(o >> 3) * HW * 8 + (o & 7)] = r;
        }
    }
}

// ---------------------------------------------------------------------------
// k_fconv v4: FUSED offset+deform conv, 512 threads / 8 waves per 16x8 tile.
// Phase A: ROUND-13 layout (ct = wave%CT, pslot = wave/CT, IPW guarded items):
// 1 weight load : IPW LDS reads : IPW MFMA per (tap,m) -- the proven ratio.
// Phase B: tap-split wave-groups + LDS partial-sum reduction; fast-path
// image-boundary masks elided (zero-fill staging makes them redundant).
// ---------------------------------------------------------------------------
template<int KD, int PAD, int HALO, int KO, int PADO, int CT>
__global__ __launch_bounds__(512) void k_fconv(
    const _Float16* __restrict__ xin,
    const _Float16* __restrict__ wto, const float* __restrict__ obias,
    const _Float16* __restrict__ wtd, const float* __restrict__ dbias,
    _Float16* __restrict__ outp)
{
    constexpr int KKD = KD * KD;          // deform taps = offset channel pairs
    constexpr int KKO = KO * KO;          // offset-conv taps
    constexpr int RB = 16 + 2 * HALO;
    constexpr int WB = 8  + 2 * HALO;
    constexpr int OP = CT * 32;
    constexpr int IPW = (CT * 4 + 7) / 8; // phase-A items per wave (guarded)
    constexpr int THALF = (KKD + 1) / 2;  // phase-B tap split point

    __shared__ half8v sm[RB * WB * 8];    // staged tile; later: partial-acc buf
    __shared__ unsigned int offs[KKD * 128];  // fp16 half2 offset per (tap,pos)

    int bi  = blockIdx.x;
    int b   = bi / 288;                   // 288 = 12 row-tiles * 24 col-tiles
    int tt  = bi % 288;
    int by0 = (tt / 24) * 16;
    int bx0 = (tt % 24) * 8;
    int ry0 = by0 - HALO;
    int rx0 = bx0 - HALO;

    const _Float16* xb = xin + (size_t)b * HW * 64;

    // ---- stage tile + halo via global_load_lds, ZERO-FILL outside image ----
    {
        _Float16* smlin = (_Float16*)sm;
        constexpr int CH = RB * WB * 8;
        for (int i0 = 0; i0 < CH; i0 += 512) {
            int i    = i0 + (int)threadIdx.x;
            int wbse = i0 + ((int)threadIdx.x & 448);    // wave-uniform chunk base
            if (i < CH) {
                int pix = i >> 3;
                int ts  = i & 7;
                int pl  = ts ^ (pix & 7);
                int r   = pix / WB;
                int cc  = pix - r * WB;
                int yr  = ry0 + r;
                int xc  = rx0 + cc;
                bool ok = (yr >= 0 && yr < HH && xc >= 0 && xc < WID);
                if (ok) {
                    const _Float16* src = xb + ((size_t)pl * HW + (size_t)(yr * WID + xc)) * 8;
                    __builtin_amdgcn_global_load_lds(src, &smlin[(size_t)wbse * 8], 16, 0, 0);
                } else {
                    *(half8v*)&smlin[(size_t)i * 8] = splat8((_Float16)0.f);
                }
            }
        }
    }
    __syncthreads();

    int lane = threadIdx.x & 63;
    int wave = threadIdx.x >> 6;          // 0..7
    int l31  = lane & 31;
    int h    = lane >> 5;
    int prow = l31 >> 3;                  // 0..3
    int pcol = l31 & 7;                   // 0..7
    int xt   = bx0 + pcol;

    // =========================== phase A: offset conv ======================
    {
        int ct    = wave % CT;            // channel tile this wave owns
        int pslot = wave / CT;            // position-slot index

        int ytA[IPW], pA[IPW];
        bool gok[IPW];
#pragma unroll
        for (int q = 0; q < IPW; q++) {
            int g = pslot * IPW + q;      // position group
            gok[q] = (g < 4);
            int gc = gok[q] ? g : 0;
            ytA[q] = by0 + gc * 4 + prow;
            pA[q]  = gc * 32 + l31;
        }

        const half8v* wbase = (const half8v*)wto;

        f32x16 accO[IPW];
#pragma unroll
        for (int q = 0; q < IPW; q++)
#pragma unroll
            for (int r = 0; r < 16; r++) accO[q][r] = 0.f;

        int ki = 0, kj = 0;
        for (int k = 0; k < KKO; k++) {
            int ccx = (xt + kj - PADO) - rx0;
            int pixA[IPW];
#pragma unroll
            for (int q = 0; q < IPW; q++)
                pixA[q] = ((ytA[q] + ki - PADO) - ry0) * WB + ccx;

#pragma unroll
            for (int m = 0; m < 4; m++) {
                int cs = m * 2 + h;
                const half8v* wp = wbase + ((size_t)k * 8 + cs) * OP;
                half8v a = wp[ct * 32 + l31];
#pragma unroll
                for (int q = 0; q < IPW; q++) {
                    half8v bf = sm[pixA[q] * 8 + (cs ^ (pixA[q] & 7))];
                    accO[q] = __builtin_amdgcn_mfma_f32_32x32x16_f16(a, bf, accO[q], 0, 0, 0);
                }
            }

            kj++;
            if (kj == KO) { kj = 0; ki++; }
        }

        // epilogue A -> LDS offsets: o = ct*32 + 8gi + 4h + 2pr; tap = o/2
#pragma unroll
        for (int q = 0; q < IPW; q++) {
            if (gok[q]) {
#pragma unroll
                for (int gi = 0; gi < 4; gi++) {
                    int obase = ct * 32 + 8 * gi + 4 * h;
#pragma unroll
                    for (int pr = 0; pr < 2; pr++) {
                        int o  = obase + 2 * pr;
                        int kt = o >> 1;
                        if (kt < KKD) {
                            half2v hv;
                            hv[0] = (_Float16)(accO[q][gi * 4 + 2 * pr]     + obias[o]);
                            hv[1] = (_Float16)(accO[q][gi * 4 + 2 * pr + 1] + obias[o + 1]);
                            *(half2v*)&offs[kt * 128 + pA[q]] = hv;
                        }
                    }
                }
            }
        }
    }
    __syncthreads();

    // =========================== phase B: deform conv ======================
    int w4   = wave & 3;
    int grp  = wave >> 2;                 // tap group: 0 -> [0,THALF), 1 -> [THALF,KKD)
    int yt   = by0 + w4 * 4 + prow;
    int p128 = w4 * 32 + l31;

    const half8v* wbase = (const half8v*)wtd;

    f32x16 acc0 = {0.f,0.f,0.f,0.f,0.f,0.f,0.f,0.f,0.f,0.f,0.f,0.f,0.f,0.f,0.f,0.f};
    f32x16 acc1 = {0.f,0.f,0.f,0.f,0.f,0.f,0.f,0.f,0.f,0.f,0.f,0.f,0.f,0.f,0.f,0.f};

    int T0 = grp ? THALF : 0;
    int T1 = grp ? KKD : THALF;
    int ki = T0 / KD, kj = T0 % KD;
    for (int k = T0; k < T1; k++) {
        // offset for this tap & position: LDS broadcast read (lane pairs share)
        half2v ov = *(const half2v*)&offs[k * 128 + p128];
        float ox = (float)ov[0];
        float oy = (float)ov[1];

        // A-frags, fragment-major: wt[k][cs][o] -> lane-contiguous 16B
        half8v a0[4], a1[4];
#pragma unroll
        for (int m = 0; m < 4; m++) {
            int cs = m * 2 + h;
            const half8v* wp = wbase + ((size_t)k * 8 + cs) * 64;   // OP = 64
            a0[m] = wp[l31];
            a1[m] = wp[32 + l31];
        }

        float py = (float)(yt + ki - PAD) + ox;
        float px = (float)(xt + kj - PAD) + oy;
        float fy = floorf(py), fx = floorf(px);
        float wy = py - fy, wx = px - fx;
        int iy0 = (int)fy, ix0 = (int)fx;
        int iy1 = iy0 + 1, ix1 = ix0 + 1;

        bool fast = (iy0 >= ry0) && (iy1 <= ry0 + RB - 1) &&
                    (ix0 >= rx0) && (ix1 <= rx0 + WB - 1);

        if (__builtin_expect(fast, 1)) {
            // zero-filled staging => image-boundary masks redundant here
            half8v w00v = splat8((_Float16)((1.f - wy) * (1.f - wx)));
            half8v w01v = splat8((_Float16)((1.f - wy) * wx));
            half8v w10v = splat8((_Float16)(wy * (1.f - wx)));
            half8v w11v = splat8((_Float16)(wy * wx));
            int p00 = (iy0 - ry0) * WB + (ix0 - rx0);
            int p01 = p00 + 1, p10 = p00 + WB, p11 = p00 + WB + 1;
            int s00 = p00 & 7, s01 = p01 & 7, s10 = p10 & 7, s11 = p11 & 7;
#pragma unroll
            for (int m = 0; m < 4; m++) {
                int cs = m * 2 + h;
                half8v c00 = sm[p00 * 8 + (cs ^ s00)];
                half8v c01 = sm[p01 * 8 + (cs ^ s01)];
                half8v c10 = sm[p10 * 8 + (cs ^ s10)];
                half8v c11 = sm[p11 * 8 + (cs ^ s11)];
                half8v bf = c00 * w00v + c01 * w01v + c10 * w10v + c11 * w11v;
                acc0 = __builtin_amdgcn_mfma_f32_32x32x16_f16(a0[m], bf, acc0, 0, 0, 0);
                acc1 = __builtin_amdgcn_mfma_f32_32x32x16_f16(a1[m], bf, acc1, 0, 0, 0);
            }
        } else {
            float m00 = (iy0 >= 0 && iy0 < HH && ix0 >= 0 && ix0 < WID) ? 1.f : 0.f;
            float m01 = (iy0 >= 0 && iy0 < HH && ix1 >= 0 && ix1 < WID) ? 1.f : 0.f;
            float m10 = (iy1 >= 0 && iy1 < HH && ix0 >= 0 && ix0 < WID) ? 1.f : 0.f;
            float m11 = (iy1 >= 0 && iy1 < HH && ix1 >= 0 && ix1 < WID) ? 1.f : 0.f;
            half8v w00v = splat8((_Float16)((1.f - wy) * (1.f - wx) * m00));
            half8v w01v = splat8((_Float16)((1.f - wy) * wx * m01));
            half8v w10v = splat8((_Float16)(wy * (1.f - wx) * m10));
            half8v w11v = splat8((_Float16)(wy * wx * m11));
            int cy0 = min(max(iy0, 0), HH - 1), cy1 = min(max(iy1, 0), HH - 1);
            int cx0 = min(max(ix0, 0), WID - 1), cx1 = min(max(ix1, 0), WID - 1);
            size_t i00 = (size_t)(cy0 * WID + cx0) * 8, i01 = (size_t)(cy0 * WID + cx1) * 8;
            size_t i10 = (size_t)(cy1 * WID + cx0) * 8, i11 = (size_t)(cy1 * WID + cx1) * 8;
#pragma unroll
            for (int m = 0; m < 4; m++) {
                const _Float16* xq = xb + (size_t)(m * 2 + h) * HW * 8;
                half8v c00 = *(const half8v*)(xq + i00);
                half8v c01 = *(const half8v*)(xq + i01);
                half8v c10 = *(const half8v*)(xq + i10);
                half8v c11 = *(const half8v*)(xq + i11);
                half8v bf = c00 * w00v + c01 * w01v + c10 * w10v + c11 * w11v;
                acc0 = __builtin_amdgcn_mfma_f32_32x32x16_f16(a0[m], bf, acc0, 0, 0, 0);
                acc1 = __builtin_amdgcn_mfma_f32_32x32x16_f16(a1[m], bf, acc1, 0, 0, 0);
            }
        }

        kj++;
        if (kj == KD) { kj = 0; ki++; }
    }

    // ---- cross-group reduction: group 1 -> LDS (sm dead), group 0 adds ----
    __syncthreads();                      // all phase-B sm reads complete
    float* red = (float*)sm;              // 256 lanes * 32 floats = 32 KB
    if (grp == 1) {
        float* dst = red + ((size_t)(w4 * 64 + lane)) * 32;
#pragma unroll
        for (int r = 0; r < 16; r++) { dst[r] = acc0[r]; dst[16 + r] = acc1[r]; }
    }
    __syncthreads();
    if (grp == 0) {
        const float* src = red + ((size_t)(w4 * 64 + lane)) * 32;
#pragma unroll
        for (int r = 0; r < 16; r++) { acc0[r] += src[r]; acc1[r] += src[16 + r]; }

        // ---- epilogue B: D: pos = l31, o = t*32 + (r&3) + 8*(r>>2) + 4h ----
        int hwp = yt * WID + xt;
        _Float16* ob = outp + (size_t)b * HW * 64 + (size_t)hwp * 8 + 4 * h;
#pragma unroll
        for (int g = 0; g < 4; g++) {
            float4 bb0 = *(const float4*)&dbias[g * 8 + 4 * h];
            half4v r0;
            r0[0] = (_Float16)(acc0[g * 4 + 0] + bb0.x);
            r0[1] = (_Float16)(acc0[g * 4 + 1] + bb0.y);
            r0[2] = (_Float16)(acc0[g * 4 + 2] + bb0.z);
            r0[3] = (_Float16)(acc0[g * 4 + 3] + bb0.w);
            *(half4v*)&ob[(size_t)g * HW * 8] = r0;
            float4 bb1 = *(const float4*)&dbias[32 + g * 8 + 4 * h];
            half4v r1;
            r1[0] = (_Float16)(acc1[g * 4 + 0] + bb1.x);
            r1[1] = (_Float16)(acc1[g * 4 + 1] + bb1.y);
            r1[2] = (_Float16)(acc1[g * 4 + 2] + bb1.z);
            r1[3] = (_Float16)(acc1[g * 4 + 3] + bb1.w);
            *(half4v*)&ob[(size_t)(4 + g) * HW * 8] = r1;
        }
    }
}

// ---------------------------------------------------------------------------
// K4 (MFMA): h = x1_final + x2; out = h @ w_out^T + b_out + x (NCHW fp32).
// ---------------------------------------------------------------------------
__global__ __launch_bounds__(256) void k_merge_mfma(
    const _Float16* __restrict__ x1f, const _Float16* __restrict__ x2,
    const float* __restrict__ xin, const _Float16* __restrict__ wt_out,
    const float* __restrict__ b_out, float* __restrict__ out)
{
    int p0  = blockIdx.x * 128;
    int b   = p0 / HW;
    int hwb = p0 % HW;

    int lane = threadIdx.x & 63;
    int wave = threadIdx.x >> 6;
    int l31  = lane & 31;
    int h    = lane >> 5;
    int pos  = hwb + wave * 32 + l31;

    const _Float16* a1 = x1f + (size_t)b * HW * 64 + (size_t)pos * 8;
    const _Float16* a2 = x2  + (size_t)b * HW * 64 + (size_t)pos * 8;

    half8v bf[4];
#pragma unroll
    for (int m = 0; m < 4; m++) {
        int cs = m * 2 + h;
        half8v u1 = *(const half8v*)&a1[(size_t)cs * HW * 8];
        half8v u2 = *(const half8v*)&a2[(size_t)cs * HW * 8];
        bf[m] = u1 + u2;
    }

    f32x16 acc[2];
#pragma unroll
    for (int tI = 0; tI < 2; tI++)
#pragma unroll
        for (int r = 0; r < 16; r++) acc[tI][r] = 0.f;

    const half8v* wbase = (const half8v*)wt_out;
#pragma unroll
    for (int m = 0; m < 4; m++) {
        int cs = m * 2 + h;
        const half8v* wp = wbase + (size_t)cs * 64;       // OP = 64
#pragma unroll
        for (int tI = 0; tI < 2; tI++) {
            half8v a = wp[tI * 32 + l31];
            acc[tI] = __builtin_amdgcn_mfma_f32_32x32x16_f16(a, bf[m], acc[tI], 0, 0, 0);
        }
    }

    size_t base = (size_t)b * CB * HW + pos;
#pragma unroll
    for (int tI = 0; tI < 2; tI++) {
#pragma unroll
        for (int gidx = 0; gidx < 4; gidx++) {
            int o0 = tI * 32 + gidx * 8 + 4 * h;
#pragma unroll
            for (int i = 0; i < 4; i++) {
                int o = o0 + i;
                out[base + (size_t)o * HW] =
                    acc[tI][gidx * 4 + i] + b_out[o] + xin[base + (size_t)o * HW];
            }
        }
    }
}

// ---------------------------------------------------------------------------
// Launch. Workspace layout unchanged (off region unused). Weights ~1.5 MB
// fragment-major; wto1 OP=128; wt_in 16KB, wt_out 8KB.
// ---------------------------------------------------------------------------
extern "C" void kernel_launch(void* const* d_in, const int* in_sizes, int n_in,
                              void* d_out, int out_size, void* d_ws, size_t ws_size,
                              hipStream_t stream)
{
    const float* x     = (const float*)d_in[0];
    const float* ln_w  = (const float*)d_in[1];
    const float* ln_b  = (const float*)d_in[2];
    const float* w_in  = (const float*)d_in[3];
    const float* b_in  = (const float*)d_in[4];
    const float* w_out = (const float*)d_in[5];
    const float* b_out = (const float*)d_in[6];
    const float* dw1   = (const float*)d_in[7];
    const float* db1   = (const float*)d_in[8];
    const float* dw2   = (const float*)d_in[9];
    const float* db2   = (const float*)d_in[10];
    const float* dw3   = (const float*)d_in[11];
    const float* db3   = (const float*)d_in[12];
    const float* ow1   = (const float*)d_in[13];
    const float* ob1   = (const float*)d_in[14];
    const float* ow2   = (const float*)d_in[15];
    const float* ob2   = (const float*)d_in[16];
    const float* ow3   = (const float*)d_in[17];
    const float* ob3   = (const float*)d_in[18];

    _Float16* x1a = (_Float16*)d_ws;
    _Float16* x1b = x1a + (size_t)NPOS * 64;
    _Float16* x2  = x1b + (size_t)NPOS * 64;
    float* off = (float*)(x2 + (size_t)NPOS * 64);       // unused (kept for layout)
    _Float16* wtd1 = (_Float16*)(off + (size_t)NPOS * 100);
    _Float16* wtd2 = wtd1 + 49 * 64 * 64;
    _Float16* wtd3 = wtd2 + 25 * 64 * 64;
    _Float16* wto1 = wtd3 +  9 * 64 * 64;
    _Float16* wto2 = wto1 + 25 * 128 * 64;   // OP=128
    _Float16* wto3 = wto2 + 25 * 64 * 64;
    _Float16* wtin = wto3 +  9 * 32 * 64;
    _Float16* wtou = wtin + 128 * 64;

    // weight prep: ONE segmented dispatch
    k_wthall<<<(677888 + 255) / 256, 256, 0, stream>>>(
        dw1, dw2, dw3, ow1, ow2, ow3, w_in, w_out,
        wtd1, wtd2, wtd3, wto1, wto2, wto3, wtin, wtou);

    // LN + 1x1 conv (MFMA)
    k_lnconv_mfma<<<NPOS / 128, 256, 0, stream>>>(x, ln_w, ln_b, wtin, b_in, x1a, x2);

    // fused offset+deform per stage (KD,PAD,HALO, KO,PADO, CT), 512 threads
    k_fconv<7, 3, 4, 5, 2, 4><<<1152, 512, 0, stream>>>(x1a, wto1, ob1, wtd1, db1, x1b);
    k_fconv<5, 2, 3, 5, 2, 2><<<1152, 512, 0, stream>>>(x1b, wto2, ob2, wtd2, db2, x1a);
    k_fconv<3, 1, 2, 3, 1, 1><<<1152, 512, 0, stream>>>(x1a, wto3, ob3, wtd3, db3, x1b);

    // merge + 1x1 conv + residual (MFMA)
    k_merge_mfma<<<NPOS / 128, 256, 0, stream>>>(x1b, x2, x, wtou, b_out, (float*)d_out);
}